// Round 12
// baseline (276.555 us; speedup 1.0000x reference)
//
#include <hip/hip_runtime.h>
#include <math.h>

#define TWO_PI 6.283185307179586f

typedef __attribute__((ext_vector_type(8))) short bf16x8;
typedef __attribute__((ext_vector_type(4))) short bf16x4;
typedef __attribute__((ext_vector_type(4))) float f32x4;

__device__ __forceinline__ short f2bf(float f) {
    unsigned u = __float_as_uint(f);
    unsigned r = (u + 0x7FFFu + ((u >> 16) & 1u)) >> 16;   // RNE
    return (short)r;
}
__device__ __forceinline__ float bf2f(short s) {
    return __uint_as_float(((unsigned)(unsigned short)s) << 16);
}

// base-4 digit reversal of a 6-bit index (radix-4 FFT output order)
__device__ __forceinline__ int dr4(int s) {
    return ((s & 3) << 4) | (s & 12) | ((s >> 4) & 3);
}

__device__ __forceinline__ void cmulw(float& xr, float& xi, float wr, float wi) {
    const float tr = xr * wr - xi * wi;
    xi = xr * wi + xi * wr;
    xr = tr;
}

// ---------------------------------------------------------------------------
// LDS radix-4 64-point FFT across a [64][W] fp32 tile.
// c = channel column; h = thread's butterfly group; NH = butterflies/thread
// (NH * num_h_groups = 16). Stage formulas identical to HW-verified rounds.
// wtr/wti: W64^m = (cos,-sin)(2pi m/64), m in [0,48).
// ---------------------------------------------------------------------------
template<int W, int NH>
__device__ __forceinline__ void fft64_dif4(float (*Lre)[W], float (*Lim)[W],
                                           const float* wtr, const float* wti,
                                           int c, int h) {
#pragma unroll
    for (int s = 0; s < 3; ++s) {
        const int q  = 16 >> (2 * s);
        const int tw = 1 << (2 * s);
        __syncthreads();
#pragma unroll
        for (int uu = 0; uu < NH; ++uu) {
            const int u = h * NH + uu;
            const int j = u & (q - 1);
            const int g = (s == 0) ? 0 : (u >> (4 - 2 * s));
            const int i0 = g * (q << 2) + j;
            const int i1 = i0 + q, i2 = i1 + q, i3 = i2 + q;
            const float a0r = Lre[i0][c], a0i = Lim[i0][c];
            const float a1r = Lre[i1][c], a1i = Lim[i1][c];
            const float a2r = Lre[i2][c], a2i = Lim[i2][c];
            const float a3r = Lre[i3][c], a3i = Lim[i3][c];
            const float t0r = a0r + a2r, t0i = a0i + a2i;
            const float t2r = a0r - a2r, t2i = a0i - a2i;
            const float t1r = a1r + a3r, t1i = a1i + a3i;
            const float dr  = a1r - a3r, di  = a1i - a3i;
            const float t3r = di, t3i = -dr;                 // -i*(a1-a3)
            Lre[i0][c] = t0r + t1r;  Lim[i0][c] = t0i + t1i;
            float y1r = t2r + t3r, y1i = t2i + t3i;
            float y2r = t0r - t1r, y2i = t0i - t1i;
            float y3r = t2r - t3r, y3i = t2i - t3i;
            const int m = j * tw;
            if (m) {
                cmulw(y1r, y1i, wtr[m], wti[m]);
                cmulw(y2r, y2i, wtr[2 * m], wti[2 * m]);
                cmulw(y3r, y3i, wtr[3 * m], wti[3 * m]);
            }
            Lre[i1][c] = y1r; Lim[i1][c] = y1i;
            Lre[i2][c] = y2r; Lim[i2][c] = y2i;
            Lre[i3][c] = y3r; Lim[i3][c] = y3i;
        }
    }
    __syncthreads();
}

template<int W, int NH>
__device__ __forceinline__ void fft64_dit4(float (*Lre)[W], float (*Lim)[W],
                                           const float* wtr, const float* wti,
                                           int c, int h) {
#pragma unroll
    for (int s = 2; s >= 0; --s) {
        const int q  = 16 >> (2 * s);
        const int tw = 1 << (2 * s);
        __syncthreads();
#pragma unroll
        for (int uu = 0; uu < NH; ++uu) {
            const int u = h * NH + uu;
            const int j = u & (q - 1);
            const int g = (s == 0) ? 0 : (u >> (4 - 2 * s));
            const int i0 = g * (q << 2) + j;
            const int i1 = i0 + q, i2 = i1 + q, i3 = i2 + q;
            float b1r = Lre[i1][c], b1i = Lim[i1][c];
            float b2r = Lre[i2][c], b2i = Lim[i2][c];
            float b3r = Lre[i3][c], b3i = Lim[i3][c];
            const int m = j * tw;
            if (m) {
                cmulw(b1r, b1i, wtr[m], -wti[m]);            // conj
                cmulw(b2r, b2i, wtr[2 * m], -wti[2 * m]);
                cmulw(b3r, b3i, wtr[3 * m], -wti[3 * m]);
            }
            const float a0r = Lre[i0][c], a0i = Lim[i0][c];
            const float u0r = a0r + b2r, u0i = a0i + b2i;
            const float u1r = a0r - b2r, u1i = a0i - b2i;
            const float u2r = b1r + b3r, u2i = b1i + b3i;
            const float dr  = b1r - b3r, di  = b1i - b3i;
            const float u3r = -di, u3i = dr;                 // +i*(b1-b3)
            Lre[i0][c] = u0r + u2r; Lim[i0][c] = u0i + u2i;
            Lre[i1][c] = u1r + u3r; Lim[i1][c] = u1i + u3i;
            Lre[i2][c] = u0r - u2r; Lim[i2][c] = u0i - u2i;
            Lre[i3][c] = u1r - u3r; Lim[i3][c] = u1i - u3i;
        }
    }
    __syncthreads();
}

#define DECODE_BCT() \
    const int b  = blockIdx.x >> 8; \
    const int dg = (blockIdx.x >> 2) & 63; \
    const int ct = blockIdx.x & 3;

#define GADDR(slot, blk, f4) \
    (((size_t)(b * 4096 + (slot)) * 512) + (size_t)((blk) * 128 + ct * 32 + (f4) * 4))

#define GADDR8(slot, blk, e8) \
    (((size_t)(b * 4096 + (slot)) * 512) + (size_t)((blk) * 128 + ct * 32 + (e8) * 8))

// 64-channel-tile decode: 8 b x 64 dg x 8 ct2 (16-channel window per blk)
#define DECODE_BCT8() \
    const int b   = blockIdx.x >> 9; \
    const int dg  = (blockIdx.x >> 3) & 63; \
    const int ct2 = blockIdx.x & 7;

#define GA64(slot, blk, off) \
    (((size_t)(b * 4096 + (slot)) * 512) + (size_t)((blk) * 128 + ct2 * 16 + (off)))

#define SETUP_TABLE48() \
    if (tid < 48) { \
        float s_, c_; \
        sincosf(TWO_PI * (float)tid / 64.0f, &s_, &c_); \
        wre[tid] = c_; wim[tid] = -s_; \
    }

// ---- forward pass A: FFT over n1 (slots 64*n1+dg), twiddle, x fp32 -> z bf16
extern "C" __global__ void __launch_bounds__(512)
fft_fwd_a(const float* __restrict__ x, short* __restrict__ zre, short* __restrict__ zim) {
    __shared__ __align__(16) float Lre[64][132];
    __shared__ __align__(16) float Lim[64][132];
    __shared__ float wre[48], wim[48];
    __shared__ float twr[64], twi[64];
    const int tid = threadIdx.x;
    SETUP_TABLE48();
    DECODE_BCT();   // dg = n2
    if (tid >= 64 && tid < 128) {
        const int s1 = tid - 64;
        float sn, cs;
        sincosf(-(TWO_PI / 4096.0f) * (float)(dg * dr4(s1)), &sn, &cs);
        twr[s1] = cs; twi[s1] = sn;
    }
    for (int idx = tid; idx < 2048; idx += 512) {
        const int n1 = idx >> 5, q = idx & 31, blk = q >> 3, f4 = q & 7;
        const int cl = blk * 32 + f4 * 4;
        const float4 v = *(const float4*)(x + GADDR(n1 * 64 + dg, blk, f4));
        *(float4*)&Lre[n1][cl] = v;
        float4 z; z.x = 0.f; z.y = 0.f; z.z = 0.f; z.w = 0.f;
        *(float4*)&Lim[n1][cl] = z;
    }
    fft64_dif4<132, 4>(Lre, Lim, wre, wim, tid & 127, tid >> 7);
    for (int idx = tid; idx < 2048; idx += 512) {
        const int s1 = idx >> 5, q = idx & 31, blk = q >> 3, f4 = q & 7;
        const int cl = blk * 32 + f4 * 4;
        const float cs = twr[s1], sn = twi[s1];
        const float4 vr = *(const float4*)&Lre[s1][cl];
        const float4 vi = *(const float4*)&Lim[s1][cl];
        bf16x4 pr, pi;
        pr[0] = f2bf(vr.x * cs - vi.x * sn);  pi[0] = f2bf(vr.x * sn + vi.x * cs);
        pr[1] = f2bf(vr.y * cs - vi.y * sn);  pi[1] = f2bf(vr.y * sn + vi.y * cs);
        pr[2] = f2bf(vr.z * cs - vi.z * sn);  pi[2] = f2bf(vr.z * sn + vi.z * cs);
        pr[3] = f2bf(vr.w * cs - vi.w * sn);  pi[3] = f2bf(vr.w * sn + vi.w * cs);
        const size_t g = GADDR(s1 * 64 + dg, blk, f4);
        *(bf16x4*)(zre + g) = pr;
        *(bf16x4*)(zim + g) = pi;
    }
}

// ---- forward pass B: FFT over n2 + fused fft4_fwd (x1/128).
// 64-channel tile [64][68], 512 threads, ~35 KB LDS -> 4 blocks/CU.
// Same sweep/barrier structure as the proven 128-wide version.
extern "C" __global__ void __launch_bounds__(512)
fft_fwd_b(short* __restrict__ zre, short* __restrict__ zim) {
    __shared__ __align__(16) float Lre[64][68];
    __shared__ __align__(16) float Lim[64][68];
    __shared__ float wre[48], wim[48];
    const int tid = threadIdx.x;
    SETUP_TABLE48();
    DECODE_BCT8();   // dg = s1
    // load: 1024 bf16x8 chunks (2 planes x 64 slots x 4 blk x 2 half)
#pragma unroll
    for (int k = 0; k < 2; ++k) {
        const int idx = tid + k * 512;
        const int p = idx >> 9;
        const int r = idx & 511;
        const int slot = r >> 3;
        const int e8 = r & 7;
        const int blk = e8 >> 1, half = e8 & 1;
        const short* src = p ? zim : zre;
        const bf16x8 v = *(const bf16x8*)(src + GA64(dg * 64 + slot, blk, half * 8));
        float* Lp = p ? &Lim[0][0] : &Lre[0][0];
        float4 a = make_float4(bf2f(v[0]), bf2f(v[1]), bf2f(v[2]), bf2f(v[3]));
        float4 bq = make_float4(bf2f(v[4]), bf2f(v[5]), bf2f(v[6]), bf2f(v[7]));
        *(float4*)(Lp + slot * 68 + e8 * 8) = a;
        *(float4*)(Lp + slot * 68 + e8 * 8 + 4) = bq;
    }
    fft64_dif4<68, 2>(Lre, Lim, wre, wim, tid & 63, tid >> 6);
    // fft4 across blocks + scale, in place: 1024 items (64 slots x 16 dl)
#pragma unroll
    for (int k = 0; k < 2; ++k) {
        const int idx = tid + k * 512;
        const int s = idx >> 4, dl = idx & 15;
        const float r0 = Lre[s][dl], r1 = Lre[s][dl + 16], r2 = Lre[s][dl + 32], r3 = Lre[s][dl + 48];
        const float m0 = Lim[s][dl], m1 = Lim[s][dl + 16], m2 = Lim[s][dl + 32], m3 = Lim[s][dl + 48];
        const float sc = 1.0f / 128.0f;
        Lre[s][dl]      = (r0 + r1 + r2 + r3) * sc;  Lim[s][dl]      = (m0 + m1 + m2 + m3) * sc;
        Lre[s][dl + 16] = (r0 + m1 - r2 - m3) * sc;  Lim[s][dl + 16] = (m0 - r1 - m2 + r3) * sc;
        Lre[s][dl + 32] = (r0 - r1 + r2 - r3) * sc;  Lim[s][dl + 32] = (m0 - m1 + m2 - m3) * sc;
        Lre[s][dl + 48] = (r0 - m1 - r2 + m3) * sc;  Lim[s][dl + 48] = (m0 + r1 - m2 - r3) * sc;
    }
    __syncthreads();
    // pack + store: 1024 chunks
#pragma unroll
    for (int k = 0; k < 2; ++k) {
        const int idx = tid + k * 512;
        const int p = idx >> 9;
        const int r = idx & 511;
        const int s2 = r >> 3;
        const int e8 = r & 7;
        const int blk = e8 >> 1, half = e8 & 1;
        const float* Lp = p ? &Lim[0][0] : &Lre[0][0];
        bf16x8 pv;
#pragma unroll
        for (int i = 0; i < 8; ++i) pv[i] = f2bf(Lp[s2 * 68 + e8 * 8 + i]);
        short* dst = p ? zim : zre;
        *(bf16x8*)(dst + GA64(dg * 64 + s2, blk, half * 8)) = pv;
    }
}

// ---- inverse pass A: fused fft4_inv (x1/128), inverse FFT over k2, twiddle.
// 64-channel tile, same structure as proven version.
extern "C" __global__ void __launch_bounds__(512)
fft_inv_a(short* __restrict__ zre, short* __restrict__ zim) {
    __shared__ __align__(16) float Lre[64][68];
    __shared__ __align__(16) float Lim[64][68];
    __shared__ float wre[48], wim[48];
    __shared__ float twr[64], twi[64];
    const int tid = threadIdx.x;
    SETUP_TABLE48();
    DECODE_BCT8();   // dg = s1
    if (tid >= 64 && tid < 128) {
        const int n2 = tid - 64;
        float sn, cs;
        sincosf((TWO_PI / 4096.0f) * (float)(n2 * dr4(dg)), &sn, &cs);
        twr[n2] = cs; twi[n2] = sn;
    }
    // load: 1024 bf16x8 chunks -> LDS fp32
#pragma unroll
    for (int k = 0; k < 2; ++k) {
        const int idx = tid + k * 512;
        const int p = idx >> 9;
        const int r = idx & 511;
        const int s2 = r >> 3;
        const int e8 = r & 7;
        const int blk = e8 >> 1, half = e8 & 1;
        const short* src = p ? zim : zre;
        const bf16x8 v = *(const bf16x8*)(src + GA64(dg * 64 + s2, blk, half * 8));
        float* Lp = p ? &Lim[0][0] : &Lre[0][0];
        float4 a = make_float4(bf2f(v[0]), bf2f(v[1]), bf2f(v[2]), bf2f(v[3]));
        float4 bq = make_float4(bf2f(v[4]), bf2f(v[5]), bf2f(v[6]), bf2f(v[7]));
        *(float4*)(Lp + s2 * 68 + e8 * 8) = a;
        *(float4*)(Lp + s2 * 68 + e8 * 8 + 4) = bq;
    }
    __syncthreads();
    // inverse fft4 across blocks + scale, in place: 1024 items
#pragma unroll
    for (int k = 0; k < 2; ++k) {
        const int idx = tid + k * 512;
        const int s = idx >> 4, dl = idx & 15;
        const float r0 = Lre[s][dl], r1 = Lre[s][dl + 16], r2 = Lre[s][dl + 32], r3 = Lre[s][dl + 48];
        const float m0 = Lim[s][dl], m1 = Lim[s][dl + 16], m2 = Lim[s][dl + 32], m3 = Lim[s][dl + 48];
        const float sc = 1.0f / 128.0f;
        Lre[s][dl]      = (r0 + r1 + r2 + r3) * sc;  Lim[s][dl]      = (m0 + m1 + m2 + m3) * sc;
        Lre[s][dl + 16] = (r0 - m1 - r2 + m3) * sc;  Lim[s][dl + 16] = (m0 + r1 - m2 - r3) * sc;
        Lre[s][dl + 32] = (r0 - r1 + r2 - r3) * sc;  Lim[s][dl + 32] = (m0 - m1 + m2 - m3) * sc;
        Lre[s][dl + 48] = (r0 + m1 - r2 - m3) * sc;  Lim[s][dl + 48] = (m0 - r1 - m2 + r3) * sc;
    }
    fft64_dit4<68, 2>(Lre, Lim, wre, wim, tid & 63, tid >> 6);
    // twiddle + pack + store: 512 (slot, e8) pairs, 1 per thread (both planes)
    {
        const int n2 = tid >> 3;
        const int e8 = tid & 7;
        const int blk = e8 >> 1, half = e8 & 1;
        const float cs = twr[n2], sn = twi[n2];
        bf16x8 pr, pi;
#pragma unroll
        for (int i = 0; i < 8; ++i) {
            const float vr = Lre[n2][e8 * 8 + i];
            const float vi = Lim[n2][e8 * 8 + i];
            pr[i] = f2bf(vr * cs - vi * sn);
            pi[i] = f2bf(vr * sn + vi * cs);
        }
        const size_t g = GA64(dg * 64 + n2, blk, half * 8);
        *(bf16x8*)(zre + g) = pr;
        *(bf16x8*)(zim + g) = pi;
    }
}

// ---- inverse pass B: inverse FFT over k1, write REAL fp32 into d_out
extern "C" __global__ void __launch_bounds__(512)
fft_inv_b(const short* __restrict__ zre, const short* __restrict__ zim,
          float* __restrict__ out) {
    __shared__ __align__(16) float Lre[64][132];
    __shared__ __align__(16) float Lim[64][132];
    __shared__ float wre[48], wim[48];
    const int tid = threadIdx.x;
    SETUP_TABLE48();
    DECODE_BCT();   // dg = n2
    for (int idx = tid; idx < 1024; idx += 512) {
        const int s1 = idx >> 4, q = idx & 15, blk = q >> 2, e8 = q & 3;
        const int cl = blk * 32 + e8 * 8;
        const size_t g = GADDR8(s1 * 64 + dg, blk, e8);
        const bf16x8 vr = *(const bf16x8*)(zre + g);
        const bf16x8 vi = *(const bf16x8*)(zim + g);
        float4 a, bq;
        a.x = bf2f(vr[0]); a.y = bf2f(vr[1]); a.z = bf2f(vr[2]); a.w = bf2f(vr[3]);
        bq.x = bf2f(vr[4]); bq.y = bf2f(vr[5]); bq.z = bf2f(vr[6]); bq.w = bf2f(vr[7]);
        *(float4*)&Lre[s1][cl] = a;
        *(float4*)&Lre[s1][cl + 4] = bq;
        a.x = bf2f(vi[0]); a.y = bf2f(vi[1]); a.z = bf2f(vi[2]); a.w = bf2f(vi[3]);
        bq.x = bf2f(vi[4]); bq.y = bf2f(vi[5]); bq.z = bf2f(vi[6]); bq.w = bf2f(vi[7]);
        *(float4*)&Lim[s1][cl] = a;
        *(float4*)&Lim[s1][cl + 4] = bq;
    }
    fft64_dit4<132, 4>(Lre, Lim, wre, wim, tid & 127, tid >> 7);
    for (int idx = tid; idx < 2048; idx += 512) {
        const int n1 = idx >> 5, q = idx & 31, blk = q >> 3, f4 = q & 7;
        const int cl = blk * 32 + f4 * 4;
        *(float4*)(out + GADDR(n1 * 64 + dg, blk, f4)) = *(const float4*)&Lre[n1][cl];
    }
}

// ---------------------------------------------------------------------------
// Weight prep: fold complex 2x2 into W_big bf16 [L][blk][n][k], in d_out.
// ---------------------------------------------------------------------------
extern "C" __global__ void __launch_bounds__(256)
wprep(const float* __restrict__ w1, const float* __restrict__ w2,
      short* __restrict__ wb) {
    const int i4  = blockIdx.x * 256 + threadIdx.x;
    const int k0  = (i4 & 63) * 4;
    const int n   = (i4 >> 6) & 255;
    const int blk = (i4 >> 14) & 3;
    const int L   = i4 >> 16;
    const float* w = L ? w2 : w1;
    bf16x4 pv;
#pragma unroll
    for (int j = 0; j < 4; ++j) {
        const int k = k0 + j;
        float v;
        if (k < 128) {
            v = (n < 128) ? w[blk * 16384 + k * 128 + n]
                          : w[65536 + blk * 16384 + k * 128 + (n - 128)];
        } else {
            v = (n < 128) ? -w[65536 + blk * 16384 + (k - 128) * 128 + n]
                          :  w[blk * 16384 + (k - 128) * 128 + (n - 128)];
        }
        pv[j] = f2bf(v);
    }
    *(bf16x4*)(wb + (size_t)i4 * 4) = pv;
}

// ---------------------------------------------------------------------------
// MFMA block-diagonal complex MLP layer over bf16 planes, in place.
// global_load_lds staging (swizzle on global source addr), double-buffered.
// ---------------------------------------------------------------------------
#define MITER 4

__device__ __forceinline__ void stage_tile(const short* __restrict__ zre,
                                           const short* __restrict__ zim,
                                           char* Abuf, int rowbase, int blk,
                                           int wave, int lane) {
#pragma unroll
    for (int it = 0; it < 4; ++it) {
        const int chunk = wave * 256 + it * 64 + lane;   // 16B chunk id, 0..2047
        const int row   = chunk >> 5;
        const unsigned kbyte = ((unsigned)((chunk & 31) << 4)) ^ ((unsigned)((row & 7) << 4));
        const int k0 = (int)(kbyte >> 1);                // element k, multiple of 8
        const short* src = (k0 < 128) ? zre : zim;
        const size_t g = (size_t)(rowbase + row) * 512 + blk * 128 + (k0 & 127);
        unsigned* lp = (unsigned*)(Abuf + (wave * 4096 + it * 1024));  // wave-uniform
        __builtin_amdgcn_global_load_lds((const unsigned*)(src + g), lp, 16, 0, 0);
    }
}

template<int LAYER>
__global__ void __launch_bounds__(512)
mlp_mfma(short* __restrict__ zre, short* __restrict__ zim,
         const short* __restrict__ wb, const float* __restrict__ bias) {
    __shared__ __align__(16) char As[2][64 * 256 * 2];   // 2 x 32 KB bf16, swizzled

    const int blk  = blockIdx.y;
    const int tid  = threadIdx.x;
    const int wave = tid >> 6;
    const int lane = tid & 63;
    const int lrow = lane & 15;
    const int lk   = lane >> 4;

    bf16x8 Bf[2][8];
#pragma unroll
    for (int nt = 0; nt < 2; ++nt) {
        const int n = wave * 32 + nt * 16 + lrow;
#pragma unroll
        for (int ks = 0; ks < 8; ++ks) {
            Bf[nt][ks] = *(const bf16x8*)(wb + ((size_t)(blk * 256 + n) * 256 + ks * 32 + lk * 8));
        }
    }

    float bv[2];
#pragma unroll
    for (int nt = 0; nt < 2; ++nt) {
        const int n = wave * 32 + nt * 16 + lrow;
        bv[nt] = (n < 128) ? bias[blk * 128 + n] : bias[512 + blk * 128 + (n - 128)];
    }

    stage_tile(zre, zim, As[0], blockIdx.x * MITER * 64, blk, wave, lane);

    for (int t = 0; t < MITER; ++t) {
        __syncthreads();

        if (t + 1 < MITER)
            stage_tile(zre, zim, As[(t + 1) & 1],
                       (blockIdx.x * MITER + t + 1) * 64, blk, wave, lane);

        const char* Ab = As[t & 1];
        const int rowbase = (blockIdx.x * MITER + t) * 64;

        f32x4 acc[4][2];
#pragma unroll
        for (int mt = 0; mt < 4; ++mt)
#pragma unroll
            for (int nt = 0; nt < 2; ++nt)
                acc[mt][nt] = (f32x4){0.f, 0.f, 0.f, 0.f};

#pragma unroll
        for (int ks = 0; ks < 8; ++ks) {
            bf16x8 af[4];
#pragma unroll
            for (int mt = 0; mt < 4; ++mt) {
                const int row = mt * 16 + lrow;
                const int k0  = ks * 32 + lk * 8;
                const unsigned byteoff =
                    ((unsigned)(row * 512 + k0 * 2)) ^ ((unsigned)((row & 7) << 4));
                af[mt] = *(const bf16x8*)(Ab + byteoff);
            }
#pragma unroll
            for (int mt = 0; mt < 4; ++mt)
#pragma unroll
                for (int nt = 0; nt < 2; ++nt)
                    acc[mt][nt] = __builtin_amdgcn_mfma_f32_16x16x32_bf16(
                        af[mt], Bf[nt][ks], acc[mt][nt], 0, 0, 0);
        }

#pragma unroll
        for (int nt = 0; nt < 2; ++nt) {
            const int n = wave * 32 + nt * 16 + lrow;
            short* dst = (n < 128) ? zre : zim;
            const int col = blk * 128 + (n & 127);
#pragma unroll
            for (int mt = 0; mt < 4; ++mt) {
#pragma unroll
                for (int r = 0; r < 4; ++r) {
                    const int row = rowbase + mt * 16 + lk * 4 + r;
                    float v = acc[mt][nt][r] + bv[nt];
                    if (LAYER == 1) {
                        v = fmaxf(v, 0.0f);
                    } else {
                        v = (v > 0.01f) ? v - 0.01f : ((v < -0.01f) ? v + 0.01f : 0.0f);
                    }
                    dst[(size_t)row * 512 + col] = f2bf(v);
                }
            }
        }
    }
}

extern "C" void kernel_launch(void* const* d_in, const int* in_sizes, int n_in,
                              void* d_out, int out_size, void* d_ws, size_t ws_size,
                              hipStream_t stream) {
    const float* x  = (const float*)d_in[0];
    const float* w1 = (const float*)d_in[1];
    const float* w2 = (const float*)d_in[2];
    const float* b1 = (const float*)d_in[3];
    const float* b2 = (const float*)d_in[4];

    float* out = (float*)d_out;
    short* zre = (short*)d_ws;            // bf16 real plane, 32 MiB
    short* zim = zre + 16777216;          // bf16 imag plane, 32 MiB
    short* wb  = (short*)d_out;           // 1 MiB W_big scratch inside d_out
    const size_t WB_L = 4ull * 256 * 256;

    wprep<<<512, 256, 0, stream>>>(w1, w2, wb);

    // forward FFT2 (ortho), radix-4 four-step; fft4+scale fused into pass B
    fft_fwd_a<<<2048, 512, 0, stream>>>(x, zre, zim);
    fft_fwd_b<<<4096, 512, 0, stream>>>(zre, zim);

    // block-diagonal complex MLP via MFMA, one dispatch per layer, in place
    mlp_mfma<1><<<dim3(32768 / (64 * MITER), 4), 512, 0, stream>>>(zre, zim, wb, b1);
    mlp_mfma<2><<<dim3(32768 / (64 * MITER), 4), 512, 0, stream>>>(zre, zim, wb + WB_L, b2);

    // inverse FFT2 (ortho), radix-4; fft4_inv+scale fused into pass A
    fft_inv_a<<<4096, 512, 0, stream>>>(zre, zim);
    fft_inv_b<<<2048, 512, 0, stream>>>(zre, zim, out);
}

// Round 13
// 224.033 us; speedup vs baseline: 1.2344x; 1.2344x over previous
//
#include <hip/hip_runtime.h>
#include <math.h>

#define TWO_PI 6.283185307179586f

typedef __attribute__((ext_vector_type(8))) short bf16x8;
typedef __attribute__((ext_vector_type(4))) short bf16x4;
typedef __attribute__((ext_vector_type(4))) float f32x4;
typedef __attribute__((ext_vector_type(4))) _Float16 h16x4;
typedef __attribute__((ext_vector_type(8))) _Float16 h16x8;

__device__ __forceinline__ short f2bf(float f) {
    unsigned u = __float_as_uint(f);
    unsigned r = (u + 0x7FFFu + ((u >> 16) & 1u)) >> 16;   // RNE
    return (short)r;
}
__device__ __forceinline__ float bf2f(short s) {
    return __uint_as_float(((unsigned)(unsigned short)s) << 16);
}

// base-4 digit reversal of a 6-bit index (radix-4 FFT output order)
__device__ __forceinline__ int dr4(int s) {
    return ((s & 3) << 4) | (s & 12) | ((s >> 4) & 3);
}

__device__ __forceinline__ void cmulw(float& xr, float& xi, float wr, float wi) {
    const float tr = xr * wr - xi * wi;
    xi = xr * wi + xi * wr;
    xr = tr;
}

// ---------------------------------------------------------------------------
// LDS radix-4 64-point FFT across a [64][W] _Float16 tile (fp32 compute,
// fp16 storage: rel err 2^-11, 4x finer than the bf16 planes themselves).
// W=136 halfs -> row stride 272 B (16B-aligned, rows offset 4 banks).
// c = channel column; h = butterfly group; NH = butterflies/thread.
// wtr/wti: W64^m = (cos,-sin)(2pi m/64), m in [0,48).
// ---------------------------------------------------------------------------
template<int W, int NH>
__device__ __forceinline__ void fft64_dif4(_Float16 (*Lre)[W], _Float16 (*Lim)[W],
                                           const float* wtr, const float* wti,
                                           int c, int h) {
#pragma unroll
    for (int s = 0; s < 3; ++s) {
        const int q  = 16 >> (2 * s);
        const int tw = 1 << (2 * s);
        __syncthreads();
#pragma unroll
        for (int uu = 0; uu < NH; ++uu) {
            const int u = h * NH + uu;
            const int j = u & (q - 1);
            const int g = (s == 0) ? 0 : (u >> (4 - 2 * s));
            const int i0 = g * (q << 2) + j;
            const int i1 = i0 + q, i2 = i1 + q, i3 = i2 + q;
            const float a0r = (float)Lre[i0][c], a0i = (float)Lim[i0][c];
            const float a1r = (float)Lre[i1][c], a1i = (float)Lim[i1][c];
            const float a2r = (float)Lre[i2][c], a2i = (float)Lim[i2][c];
            const float a3r = (float)Lre[i3][c], a3i = (float)Lim[i3][c];
            const float t0r = a0r + a2r, t0i = a0i + a2i;
            const float t2r = a0r - a2r, t2i = a0i - a2i;
            const float t1r = a1r + a3r, t1i = a1i + a3i;
            const float dr  = a1r - a3r, di  = a1i - a3i;
            const float t3r = di, t3i = -dr;                 // -i*(a1-a3)
            Lre[i0][c] = (_Float16)(t0r + t1r);  Lim[i0][c] = (_Float16)(t0i + t1i);
            float y1r = t2r + t3r, y1i = t2i + t3i;
            float y2r = t0r - t1r, y2i = t0i - t1i;
            float y3r = t2r - t3r, y3i = t2i - t3i;
            const int m = j * tw;
            if (m) {
                cmulw(y1r, y1i, wtr[m], wti[m]);
                cmulw(y2r, y2i, wtr[2 * m], wti[2 * m]);
                cmulw(y3r, y3i, wtr[3 * m], wti[3 * m]);
            }
            Lre[i1][c] = (_Float16)y1r; Lim[i1][c] = (_Float16)y1i;
            Lre[i2][c] = (_Float16)y2r; Lim[i2][c] = (_Float16)y2i;
            Lre[i3][c] = (_Float16)y3r; Lim[i3][c] = (_Float16)y3i;
        }
    }
    __syncthreads();
}

template<int W, int NH>
__device__ __forceinline__ void fft64_dit4(_Float16 (*Lre)[W], _Float16 (*Lim)[W],
                                           const float* wtr, const float* wti,
                                           int c, int h) {
#pragma unroll
    for (int s = 2; s >= 0; --s) {
        const int q  = 16 >> (2 * s);
        const int tw = 1 << (2 * s);
        __syncthreads();
#pragma unroll
        for (int uu = 0; uu < NH; ++uu) {
            const int u = h * NH + uu;
            const int j = u & (q - 1);
            const int g = (s == 0) ? 0 : (u >> (4 - 2 * s));
            const int i0 = g * (q << 2) + j;
            const int i1 = i0 + q, i2 = i1 + q, i3 = i2 + q;
            float b1r = (float)Lre[i1][c], b1i = (float)Lim[i1][c];
            float b2r = (float)Lre[i2][c], b2i = (float)Lim[i2][c];
            float b3r = (float)Lre[i3][c], b3i = (float)Lim[i3][c];
            const int m = j * tw;
            if (m) {
                cmulw(b1r, b1i, wtr[m], -wti[m]);            // conj
                cmulw(b2r, b2i, wtr[2 * m], -wti[2 * m]);
                cmulw(b3r, b3i, wtr[3 * m], -wti[3 * m]);
            }
            const float a0r = (float)Lre[i0][c], a0i = (float)Lim[i0][c];
            const float u0r = a0r + b2r, u0i = a0i + b2i;
            const float u1r = a0r - b2r, u1i = a0i - b2i;
            const float u2r = b1r + b3r, u2i = b1i + b3i;
            const float dr  = b1r - b3r, di  = b1i - b3i;
            const float u3r = -di, u3i = dr;                 // +i*(b1-b3)
            Lre[i0][c] = (_Float16)(u0r + u2r); Lim[i0][c] = (_Float16)(u0i + u2i);
            Lre[i1][c] = (_Float16)(u1r + u3r); Lim[i1][c] = (_Float16)(u1i + u3i);
            Lre[i2][c] = (_Float16)(u0r - u2r); Lim[i2][c] = (_Float16)(u0i - u2i);
            Lre[i3][c] = (_Float16)(u1r - u3r); Lim[i3][c] = (_Float16)(u1i - u3i);
        }
    }
    __syncthreads();
}

#define DECODE_BCT() \
    const int b  = blockIdx.x >> 8; \
    const int dg = (blockIdx.x >> 2) & 63; \
    const int ct = blockIdx.x & 3;

#define GADDR(slot, blk, f4) \
    (((size_t)(b * 4096 + (slot)) * 512) + (size_t)((blk) * 128 + ct * 32 + (f4) * 4))

#define GADDR8(slot, blk, e8) \
    (((size_t)(b * 4096 + (slot)) * 512) + (size_t)((blk) * 128 + ct * 32 + (e8) * 8))

#define SETUP_TABLE48() \
    if (tid < 48) { \
        float s_, c_; \
        sincosf(TWO_PI * (float)tid / 64.0f, &s_, &c_); \
        wre[tid] = c_; wim[tid] = -s_; \
    }

// ---- forward pass A: FFT over n1 (slots 64*n1+dg), twiddle, x fp32 -> z bf16
extern "C" __global__ void __launch_bounds__(512)
fft_fwd_a(const float* __restrict__ x, short* __restrict__ zre, short* __restrict__ zim) {
    __shared__ __align__(16) _Float16 Lre[64][136];
    __shared__ __align__(16) _Float16 Lim[64][136];
    __shared__ float wre[48], wim[48];
    __shared__ float twr[64], twi[64];
    const int tid = threadIdx.x;
    SETUP_TABLE48();
    DECODE_BCT();   // dg = n2
    if (tid >= 64 && tid < 128) {
        const int s1 = tid - 64;
        float sn, cs;
        sincosf(-(TWO_PI / 4096.0f) * (float)(dg * dr4(s1)), &sn, &cs);
        twr[s1] = cs; twi[s1] = sn;
    }
    for (int idx = tid; idx < 2048; idx += 512) {
        const int n1 = idx >> 5, q = idx & 31, blk = q >> 3, f4 = q & 7;
        const int cl = blk * 32 + f4 * 4;
        const float4 v = *(const float4*)(x + GADDR(n1 * 64 + dg, blk, f4));
        h16x4 hv, hz;
        hv[0] = (_Float16)v.x; hv[1] = (_Float16)v.y;
        hv[2] = (_Float16)v.z; hv[3] = (_Float16)v.w;
        hz[0] = (_Float16)0.f; hz[1] = (_Float16)0.f;
        hz[2] = (_Float16)0.f; hz[3] = (_Float16)0.f;
        *(h16x4*)&Lre[n1][cl] = hv;
        *(h16x4*)&Lim[n1][cl] = hz;
    }
    fft64_dif4<136, 4>(Lre, Lim, wre, wim, tid & 127, tid >> 7);
    for (int idx = tid; idx < 2048; idx += 512) {
        const int s1 = idx >> 5, q = idx & 31, blk = q >> 3, f4 = q & 7;
        const int cl = blk * 32 + f4 * 4;
        const float cs = twr[s1], sn = twi[s1];
        const h16x4 hr = *(const h16x4*)&Lre[s1][cl];
        const h16x4 hi = *(const h16x4*)&Lim[s1][cl];
        bf16x4 pr, pi;
#pragma unroll
        for (int i = 0; i < 4; ++i) {
            const float vr = (float)hr[i], vi = (float)hi[i];
            pr[i] = f2bf(vr * cs - vi * sn);
            pi[i] = f2bf(vr * sn + vi * cs);
        }
        const size_t g = GADDR(s1 * 64 + dg, blk, f4);
        *(bf16x4*)(zre + g) = pr;
        *(bf16x4*)(zim + g) = pi;
    }
}

// ---- forward pass B: FFT over n2 (contiguous slots) + fused fft4_fwd (x1/128)
extern "C" __global__ void __launch_bounds__(512)
fft_fwd_b(short* __restrict__ zre, short* __restrict__ zim) {
    __shared__ __align__(16) _Float16 Lre[64][136];
    __shared__ __align__(16) _Float16 Lim[64][136];
    __shared__ float wre[48], wim[48];
    const int tid = threadIdx.x;
    SETUP_TABLE48();
    DECODE_BCT();   // dg = s1
    for (int idx = tid; idx < 1024; idx += 512) {
        const int n2 = idx >> 4, q = idx & 15, blk = q >> 2, e8 = q & 3;
        const int cl = blk * 32 + e8 * 8;
        const size_t g = GADDR8(dg * 64 + n2, blk, e8);
        const bf16x8 vr = *(const bf16x8*)(zre + g);
        const bf16x8 vi = *(const bf16x8*)(zim + g);
        h16x8 hr, hi;
#pragma unroll
        for (int i = 0; i < 8; ++i) {
            hr[i] = (_Float16)bf2f(vr[i]);
            hi[i] = (_Float16)bf2f(vi[i]);
        }
        *(h16x8*)&Lre[n2][cl] = hr;
        *(h16x8*)&Lim[n2][cl] = hi;
    }
    fft64_dif4<136, 4>(Lre, Lim, wre, wim, tid & 127, tid >> 7);
    for (int idx = tid; idx < 2048; idx += 512) {
        const int s = idx >> 5, dl = idx & 31;
        const float r0 = (float)Lre[s][dl],      r1 = (float)Lre[s][dl + 32];
        const float r2 = (float)Lre[s][dl + 64], r3 = (float)Lre[s][dl + 96];
        const float m0 = (float)Lim[s][dl],      m1 = (float)Lim[s][dl + 32];
        const float m2 = (float)Lim[s][dl + 64], m3 = (float)Lim[s][dl + 96];
        const float sc = 1.0f / 128.0f;
        Lre[s][dl]      = (_Float16)((r0 + r1 + r2 + r3) * sc);
        Lim[s][dl]      = (_Float16)((m0 + m1 + m2 + m3) * sc);
        Lre[s][dl + 32] = (_Float16)((r0 + m1 - r2 - m3) * sc);
        Lim[s][dl + 32] = (_Float16)((m0 - r1 - m2 + r3) * sc);
        Lre[s][dl + 64] = (_Float16)((r0 - r1 + r2 - r3) * sc);
        Lim[s][dl + 64] = (_Float16)((m0 - m1 + m2 - m3) * sc);
        Lre[s][dl + 96] = (_Float16)((r0 - m1 - r2 + m3) * sc);
        Lim[s][dl + 96] = (_Float16)((m0 + r1 - m2 - r3) * sc);
    }
    __syncthreads();
    for (int idx = tid; idx < 1024; idx += 512) {
        const int s2 = idx >> 4, q = idx & 15, blk = q >> 2, e8 = q & 3;
        const int cl = blk * 32 + e8 * 8;
        const h16x8 hr = *(const h16x8*)&Lre[s2][cl];
        const h16x8 hi = *(const h16x8*)&Lim[s2][cl];
        bf16x8 pr, pi;
#pragma unroll
        for (int i = 0; i < 8; ++i) {
            pr[i] = f2bf((float)hr[i]);
            pi[i] = f2bf((float)hi[i]);
        }
        const size_t g = GADDR8(dg * 64 + s2, blk, e8);
        *(bf16x8*)(zre + g) = pr;
        *(bf16x8*)(zim + g) = pi;
    }
}

// ---- inverse pass A: fused fft4_inv (x1/128), inverse FFT over k2, twiddle
extern "C" __global__ void __launch_bounds__(512)
fft_inv_a(short* __restrict__ zre, short* __restrict__ zim) {
    __shared__ __align__(16) _Float16 Lre[64][136];
    __shared__ __align__(16) _Float16 Lim[64][136];
    __shared__ float wre[48], wim[48];
    __shared__ float twr[64], twi[64];
    const int tid = threadIdx.x;
    SETUP_TABLE48();
    DECODE_BCT();   // dg = s1
    if (tid >= 64 && tid < 128) {
        const int n2 = tid - 64;
        float sn, cs;
        sincosf((TWO_PI / 4096.0f) * (float)(n2 * dr4(dg)), &sn, &cs);
        twr[n2] = cs; twi[n2] = sn;
    }
    for (int idx = tid; idx < 1024; idx += 512) {
        const int s2 = idx >> 4, q = idx & 15, blk = q >> 2, e8 = q & 3;
        const int cl = blk * 32 + e8 * 8;
        const size_t g = GADDR8(dg * 64 + s2, blk, e8);
        const bf16x8 vr = *(const bf16x8*)(zre + g);
        const bf16x8 vi = *(const bf16x8*)(zim + g);
        h16x8 hr, hi;
#pragma unroll
        for (int i = 0; i < 8; ++i) {
            hr[i] = (_Float16)bf2f(vr[i]);
            hi[i] = (_Float16)bf2f(vi[i]);
        }
        *(h16x8*)&Lre[s2][cl] = hr;
        *(h16x8*)&Lim[s2][cl] = hi;
    }
    __syncthreads();
    for (int idx = tid; idx < 2048; idx += 512) {
        const int s = idx >> 5, dl = idx & 31;
        const float r0 = (float)Lre[s][dl],      r1 = (float)Lre[s][dl + 32];
        const float r2 = (float)Lre[s][dl + 64], r3 = (float)Lre[s][dl + 96];
        const float m0 = (float)Lim[s][dl],      m1 = (float)Lim[s][dl + 32];
        const float m2 = (float)Lim[s][dl + 64], m3 = (float)Lim[s][dl + 96];
        const float sc = 1.0f / 128.0f;
        Lre[s][dl]      = (_Float16)((r0 + r1 + r2 + r3) * sc);
        Lim[s][dl]      = (_Float16)((m0 + m1 + m2 + m3) * sc);
        Lre[s][dl + 32] = (_Float16)((r0 - m1 - r2 + m3) * sc);
        Lim[s][dl + 32] = (_Float16)((m0 + r1 - m2 - r3) * sc);
        Lre[s][dl + 64] = (_Float16)((r0 - r1 + r2 - r3) * sc);
        Lim[s][dl + 64] = (_Float16)((m0 - m1 + m2 - m3) * sc);
        Lre[s][dl + 96] = (_Float16)((r0 + m1 - r2 - m3) * sc);
        Lim[s][dl + 96] = (_Float16)((m0 - r1 - m2 + r3) * sc);
    }
    fft64_dit4<136, 4>(Lre, Lim, wre, wim, tid & 127, tid >> 7);
    for (int idx = tid; idx < 2048; idx += 512) {
        const int n2 = idx >> 5, q = idx & 31, blk = q >> 3, f4 = q & 7;
        const int cl = blk * 32 + f4 * 4;
        const float cs = twr[n2], sn = twi[n2];
        const h16x4 hr = *(const h16x4*)&Lre[n2][cl];
        const h16x4 hi = *(const h16x4*)&Lim[n2][cl];
        bf16x4 pr, pi;
#pragma unroll
        for (int i = 0; i < 4; ++i) {
            const float vr = (float)hr[i], vi = (float)hi[i];
            pr[i] = f2bf(vr * cs - vi * sn);
            pi[i] = f2bf(vr * sn + vi * cs);
        }
        const size_t g = GADDR(dg * 64 + n2, blk, f4);
        *(bf16x4*)(zre + g) = pr;
        *(bf16x4*)(zim + g) = pi;
    }
}

// ---- inverse pass B: inverse FFT over k1, write REAL fp32 into d_out
extern "C" __global__ void __launch_bounds__(512)
fft_inv_b(const short* __restrict__ zre, const short* __restrict__ zim,
          float* __restrict__ out) {
    __shared__ __align__(16) _Float16 Lre[64][136];
    __shared__ __align__(16) _Float16 Lim[64][136];
    __shared__ float wre[48], wim[48];
    const int tid = threadIdx.x;
    SETUP_TABLE48();
    DECODE_BCT();   // dg = n2
    for (int idx = tid; idx < 1024; idx += 512) {
        const int s1 = idx >> 4, q = idx & 15, blk = q >> 2, e8 = q & 3;
        const int cl = blk * 32 + e8 * 8;
        const size_t g = GADDR8(s1 * 64 + dg, blk, e8);
        const bf16x8 vr = *(const bf16x8*)(zre + g);
        const bf16x8 vi = *(const bf16x8*)(zim + g);
        h16x8 hr, hi;
#pragma unroll
        for (int i = 0; i < 8; ++i) {
            hr[i] = (_Float16)bf2f(vr[i]);
            hi[i] = (_Float16)bf2f(vi[i]);
        }
        *(h16x8*)&Lre[s1][cl] = hr;
        *(h16x8*)&Lim[s1][cl] = hi;
    }
    fft64_dit4<136, 4>(Lre, Lim, wre, wim, tid & 127, tid >> 7);
    for (int idx = tid; idx < 2048; idx += 512) {
        const int n1 = idx >> 5, q = idx & 31, blk = q >> 3, f4 = q & 7;
        const int cl = blk * 32 + f4 * 4;
        const h16x4 hr = *(const h16x4*)&Lre[n1][cl];
        float4 o;
        o.x = (float)hr[0]; o.y = (float)hr[1];
        o.z = (float)hr[2]; o.w = (float)hr[3];
        *(float4*)(out + GADDR(n1 * 64 + dg, blk, f4)) = o;
    }
}

// ---------------------------------------------------------------------------
// Weight prep: fold complex 2x2 into W_big bf16 [L][blk][n][k], in d_out.
// ---------------------------------------------------------------------------
extern "C" __global__ void __launch_bounds__(256)
wprep(const float* __restrict__ w1, const float* __restrict__ w2,
      short* __restrict__ wb) {
    const int i4  = blockIdx.x * 256 + threadIdx.x;
    const int k0  = (i4 & 63) * 4;
    const int n   = (i4 >> 6) & 255;
    const int blk = (i4 >> 14) & 3;
    const int L   = i4 >> 16;
    const float* w = L ? w2 : w1;
    bf16x4 pv;
#pragma unroll
    for (int j = 0; j < 4; ++j) {
        const int k = k0 + j;
        float v;
        if (k < 128) {
            v = (n < 128) ? w[blk * 16384 + k * 128 + n]
                          : w[65536 + blk * 16384 + k * 128 + (n - 128)];
        } else {
            v = (n < 128) ? -w[65536 + blk * 16384 + (k - 128) * 128 + n]
                          :  w[blk * 16384 + (k - 128) * 128 + (n - 128)];
        }
        pv[j] = f2bf(v);
    }
    *(bf16x4*)(wb + (size_t)i4 * 4) = pv;
}

// ---------------------------------------------------------------------------
// MFMA block-diagonal complex MLP layer over bf16 planes, in place.
// global_load_lds staging (swizzle on global source addr), double-buffered.
// ---------------------------------------------------------------------------
#define MITER 4

__device__ __forceinline__ void stage_tile(const short* __restrict__ zre,
                                           const short* __restrict__ zim,
                                           char* Abuf, int rowbase, int blk,
                                           int wave, int lane) {
#pragma unroll
    for (int it = 0; it < 4; ++it) {
        const int chunk = wave * 256 + it * 64 + lane;   // 16B chunk id, 0..2047
        const int row   = chunk >> 5;
        const unsigned kbyte = ((unsigned)((chunk & 31) << 4)) ^ ((unsigned)((row & 7) << 4));
        const int k0 = (int)(kbyte >> 1);                // element k, multiple of 8
        const short* src = (k0 < 128) ? zre : zim;
        const size_t g = (size_t)(rowbase + row) * 512 + blk * 128 + (k0 & 127);
        unsigned* lp = (unsigned*)(Abuf + (wave * 4096 + it * 1024));  // wave-uniform
        __builtin_amdgcn_global_load_lds((const unsigned*)(src + g), lp, 16, 0, 0);
    }
}

template<int LAYER>
__global__ void __launch_bounds__(512)
mlp_mfma(short* __restrict__ zre, short* __restrict__ zim,
         const short* __restrict__ wb, const float* __restrict__ bias) {
    __shared__ __align__(16) char As[2][64 * 256 * 2];   // 2 x 32 KB bf16, swizzled

    const int blk  = blockIdx.y;
    const int tid  = threadIdx.x;
    const int wave = tid >> 6;
    const int lane = tid & 63;
    const int lrow = lane & 15;
    const int lk   = lane >> 4;

    bf16x8 Bf[2][8];
#pragma unroll
    for (int nt = 0; nt < 2; ++nt) {
        const int n = wave * 32 + nt * 16 + lrow;
#pragma unroll
        for (int ks = 0; ks < 8; ++ks) {
            Bf[nt][ks] = *(const bf16x8*)(wb + ((size_t)(blk * 256 + n) * 256 + ks * 32 + lk * 8));
        }
    }

    float bv[2];
#pragma unroll
    for (int nt = 0; nt < 2; ++nt) {
        const int n = wave * 32 + nt * 16 + lrow;
        bv[nt] = (n < 128) ? bias[blk * 128 + n] : bias[512 + blk * 128 + (n - 128)];
    }

    stage_tile(zre, zim, As[0], blockIdx.x * MITER * 64, blk, wave, lane);

    for (int t = 0; t < MITER; ++t) {
        __syncthreads();

        if (t + 1 < MITER)
            stage_tile(zre, zim, As[(t + 1) & 1],
                       (blockIdx.x * MITER + t + 1) * 64, blk, wave, lane);

        const char* Ab = As[t & 1];
        const int rowbase = (blockIdx.x * MITER + t) * 64;

        f32x4 acc[4][2];
#pragma unroll
        for (int mt = 0; mt < 4; ++mt)
#pragma unroll
            for (int nt = 0; nt < 2; ++nt)
                acc[mt][nt] = (f32x4){0.f, 0.f, 0.f, 0.f};

#pragma unroll
        for (int ks = 0; ks < 8; ++ks) {
            bf16x8 af[4];
#pragma unroll
            for (int mt = 0; mt < 4; ++mt) {
                const int row = mt * 16 + lrow;
                const int k0  = ks * 32 + lk * 8;
                const unsigned byteoff =
                    ((unsigned)(row * 512 + k0 * 2)) ^ ((unsigned)((row & 7) << 4));
                af[mt] = *(const bf16x8*)(Ab + byteoff);
            }
#pragma unroll
            for (int mt = 0; mt < 4; ++mt)
#pragma unroll
                for (int nt = 0; nt < 2; ++nt)
                    acc[mt][nt] = __builtin_amdgcn_mfma_f32_16x16x32_bf16(
                        af[mt], Bf[nt][ks], acc[mt][nt], 0, 0, 0);
        }

#pragma unroll
        for (int nt = 0; nt < 2; ++nt) {
            const int n = wave * 32 + nt * 16 + lrow;
            short* dst = (n < 128) ? zre : zim;
            const int col = blk * 128 + (n & 127);
#pragma unroll
            for (int mt = 0; mt < 4; ++mt) {
#pragma unroll
                for (int r = 0; r < 4; ++r) {
                    const int row = rowbase + mt * 16 + lk * 4 + r;
                    float v = acc[mt][nt][r] + bv[nt];
                    if (LAYER == 1) {
                        v = fmaxf(v, 0.0f);
                    } else {
                        v = (v > 0.01f) ? v - 0.01f : ((v < -0.01f) ? v + 0.01f : 0.0f);
                    }
                    dst[(size_t)row * 512 + col] = f2bf(v);
                }
            }
        }
    }
}

extern "C" void kernel_launch(void* const* d_in, const int* in_sizes, int n_in,
                              void* d_out, int out_size, void* d_ws, size_t ws_size,
                              hipStream_t stream) {
    const float* x  = (const float*)d_in[0];
    const float* w1 = (const float*)d_in[1];
    const float* w2 = (const float*)d_in[2];
    const float* b1 = (const float*)d_in[3];
    const float* b2 = (const float*)d_in[4];

    float* out = (float*)d_out;
    short* zre = (short*)d_ws;            // bf16 real plane, 32 MiB
    short* zim = zre + 16777216;          // bf16 imag plane, 32 MiB
    short* wb  = (short*)d_out;           // 1 MiB W_big scratch inside d_out
    const size_t WB_L = 4ull * 256 * 256;

    wprep<<<512, 256, 0, stream>>>(w1, w2, wb);

    // forward FFT2 (ortho), radix-4 four-step; fft4+scale fused into pass B
    fft_fwd_a<<<2048, 512, 0, stream>>>(x, zre, zim);
    fft_fwd_b<<<2048, 512, 0, stream>>>(zre, zim);

    // block-diagonal complex MLP via MFMA, one dispatch per layer, in place
    mlp_mfma<1><<<dim3(32768 / (64 * MITER), 4), 512, 0, stream>>>(zre, zim, wb, b1);
    mlp_mfma<2><<<dim3(32768 / (64 * MITER), 4), 512, 0, stream>>>(zre, zim, wb + WB_L, b2);

    // inverse FFT2 (ortho), radix-4; fft4_inv+scale fused into pass A
    fft_inv_a<<<2048, 512, 0, stream>>>(zre, zim);
    fft_inv_b<<<2048, 512, 0, stream>>>(zre, zim, out);
}

// Round 14
// 221.289 us; speedup vs baseline: 1.2497x; 1.0124x over previous
//
#include <hip/hip_runtime.h>
#include <math.h>

#define TWO_PI 6.283185307179586f

typedef __attribute__((ext_vector_type(8))) short bf16x8;
typedef __attribute__((ext_vector_type(4))) short bf16x4;
typedef __attribute__((ext_vector_type(4))) float f32x4;
typedef __attribute__((ext_vector_type(4))) _Float16 h16x4;
typedef __attribute__((ext_vector_type(8))) _Float16 h16x8;

__device__ __forceinline__ short f2bf(float f) {
    unsigned u = __float_as_uint(f);
    unsigned r = (u + 0x7FFFu + ((u >> 16) & 1u)) >> 16;   // RNE
    return (short)r;
}
__device__ __forceinline__ float bf2f(short s) {
    return __uint_as_float(((unsigned)(unsigned short)s) << 16);
}

// base-4 digit reversal of a 6-bit index (radix-4 FFT output order)
__device__ __forceinline__ int dr4(int s) {
    return ((s & 3) << 4) | (s & 12) | ((s >> 4) & 3);
}

__device__ __forceinline__ void cmulw(float& xr, float& xi, float wr, float wi) {
    const float tr = xr * wr - xi * wi;
    xi = xr * wi + xi * wr;
    xr = tr;
}

// ---------------------------------------------------------------------------
// LDS radix-4 64-point FFT, CHANNEL-VECTORIZED: each thread owns 4 adjacent
// channels (one h16x4 = 8B ds op) and ONE butterfly per stage (h in [0,16)).
// fp32 compute, fp16 storage. W=136 halfs (272B row stride, 16B aligned).
// Same stage math / barrier structure as the HW-verified scalar version.
// wtr/wti: W64^m = (cos,-sin)(2pi m/64), m in [0,48).
// ---------------------------------------------------------------------------
template<int W>
__device__ __forceinline__ void fft64_dif4v(_Float16 (*Lre)[W], _Float16 (*Lim)[W],
                                            const float* wtr, const float* wti,
                                            int c4, int h) {
#pragma unroll
    for (int s = 0; s < 3; ++s) {
        const int q  = 16 >> (2 * s);
        const int tw = 1 << (2 * s);
        __syncthreads();
        const int j = h & (q - 1);
        const int g = (s == 0) ? 0 : (h >> (4 - 2 * s));
        const int i0 = g * (q << 2) + j;
        const int i1 = i0 + q, i2 = i1 + q, i3 = i2 + q;
        const h16x4 A0r = *(const h16x4*)&Lre[i0][c4], A0i = *(const h16x4*)&Lim[i0][c4];
        const h16x4 A1r = *(const h16x4*)&Lre[i1][c4], A1i = *(const h16x4*)&Lim[i1][c4];
        const h16x4 A2r = *(const h16x4*)&Lre[i2][c4], A2i = *(const h16x4*)&Lim[i2][c4];
        const h16x4 A3r = *(const h16x4*)&Lre[i3][c4], A3i = *(const h16x4*)&Lim[i3][c4];
        const int m = j * tw;
        const float w1r = wtr[m],     w1i = wti[m];
        const float w2r = wtr[2 * m], w2i = wti[2 * m];
        const float w3r = wtr[3 * m], w3i = wti[3 * m];
        h16x4 O0r, O0i, O1r, O1i, O2r, O2i, O3r, O3i;
#pragma unroll
        for (int e = 0; e < 4; ++e) {
            const float a0r = (float)A0r[e], a0i = (float)A0i[e];
            const float a1r = (float)A1r[e], a1i = (float)A1i[e];
            const float a2r = (float)A2r[e], a2i = (float)A2i[e];
            const float a3r = (float)A3r[e], a3i = (float)A3i[e];
            const float t0r = a0r + a2r, t0i = a0i + a2i;
            const float t2r = a0r - a2r, t2i = a0i - a2i;
            const float t1r = a1r + a3r, t1i = a1i + a3i;
            const float dr  = a1r - a3r, di  = a1i - a3i;
            const float t3r = di, t3i = -dr;                 // -i*(a1-a3)
            O0r[e] = (_Float16)(t0r + t1r);  O0i[e] = (_Float16)(t0i + t1i);
            float y1r = t2r + t3r, y1i = t2i + t3i;
            float y2r = t0r - t1r, y2i = t0i - t1i;
            float y3r = t2r - t3r, y3i = t2i - t3i;
            if (m) {
                cmulw(y1r, y1i, w1r, w1i);
                cmulw(y2r, y2i, w2r, w2i);
                cmulw(y3r, y3i, w3r, w3i);
            }
            O1r[e] = (_Float16)y1r; O1i[e] = (_Float16)y1i;
            O2r[e] = (_Float16)y2r; O2i[e] = (_Float16)y2i;
            O3r[e] = (_Float16)y3r; O3i[e] = (_Float16)y3i;
        }
        *(h16x4*)&Lre[i0][c4] = O0r;  *(h16x4*)&Lim[i0][c4] = O0i;
        *(h16x4*)&Lre[i1][c4] = O1r;  *(h16x4*)&Lim[i1][c4] = O1i;
        *(h16x4*)&Lre[i2][c4] = O2r;  *(h16x4*)&Lim[i2][c4] = O2i;
        *(h16x4*)&Lre[i3][c4] = O3r;  *(h16x4*)&Lim[i3][c4] = O3i;
    }
    __syncthreads();
}

template<int W>
__device__ __forceinline__ void fft64_dit4v(_Float16 (*Lre)[W], _Float16 (*Lim)[W],
                                            const float* wtr, const float* wti,
                                            int c4, int h) {
#pragma unroll
    for (int s = 2; s >= 0; --s) {
        const int q  = 16 >> (2 * s);
        const int tw = 1 << (2 * s);
        __syncthreads();
        const int j = h & (q - 1);
        const int g = (s == 0) ? 0 : (h >> (4 - 2 * s));
        const int i0 = g * (q << 2) + j;
        const int i1 = i0 + q, i2 = i1 + q, i3 = i2 + q;
        const h16x4 A0r = *(const h16x4*)&Lre[i0][c4], A0i = *(const h16x4*)&Lim[i0][c4];
        const h16x4 A1r = *(const h16x4*)&Lre[i1][c4], A1i = *(const h16x4*)&Lim[i1][c4];
        const h16x4 A2r = *(const h16x4*)&Lre[i2][c4], A2i = *(const h16x4*)&Lim[i2][c4];
        const h16x4 A3r = *(const h16x4*)&Lre[i3][c4], A3i = *(const h16x4*)&Lim[i3][c4];
        const int m = j * tw;
        const float w1r = wtr[m],     w1i = -wti[m];         // conj
        const float w2r = wtr[2 * m], w2i = -wti[2 * m];
        const float w3r = wtr[3 * m], w3i = -wti[3 * m];
        h16x4 O0r, O0i, O1r, O1i, O2r, O2i, O3r, O3i;
#pragma unroll
        for (int e = 0; e < 4; ++e) {
            float b1r = (float)A1r[e], b1i = (float)A1i[e];
            float b2r = (float)A2r[e], b2i = (float)A2i[e];
            float b3r = (float)A3r[e], b3i = (float)A3i[e];
            if (m) {
                cmulw(b1r, b1i, w1r, w1i);
                cmulw(b2r, b2i, w2r, w2i);
                cmulw(b3r, b3i, w3r, w3i);
            }
            const float a0r = (float)A0r[e], a0i = (float)A0i[e];
            const float u0r = a0r + b2r, u0i = a0i + b2i;
            const float u1r = a0r - b2r, u1i = a0i - b2i;
            const float u2r = b1r + b3r, u2i = b1i + b3i;
            const float dr  = b1r - b3r, di  = b1i - b3i;
            const float u3r = -di, u3i = dr;                 // +i*(b1-b3)
            O0r[e] = (_Float16)(u0r + u2r); O0i[e] = (_Float16)(u0i + u2i);
            O1r[e] = (_Float16)(u1r + u3r); O1i[e] = (_Float16)(u1i + u3i);
            O2r[e] = (_Float16)(u0r - u2r); O2i[e] = (_Float16)(u0i - u2i);
            O3r[e] = (_Float16)(u1r - u3r); O3i[e] = (_Float16)(u1i - u3i);
        }
        *(h16x4*)&Lre[i0][c4] = O0r;  *(h16x4*)&Lim[i0][c4] = O0i;
        *(h16x4*)&Lre[i1][c4] = O1r;  *(h16x4*)&Lim[i1][c4] = O1i;
        *(h16x4*)&Lre[i2][c4] = O2r;  *(h16x4*)&Lim[i2][c4] = O2i;
        *(h16x4*)&Lre[i3][c4] = O3r;  *(h16x4*)&Lim[i3][c4] = O3i;
    }
    __syncthreads();
}

#define DECODE_BCT() \
    const int b  = blockIdx.x >> 8; \
    const int dg = (blockIdx.x >> 2) & 63; \
    const int ct = blockIdx.x & 3;

#define GADDR(slot, blk, f4) \
    (((size_t)(b * 4096 + (slot)) * 512) + (size_t)((blk) * 128 + ct * 32 + (f4) * 4))

#define GADDR8(slot, blk, e8) \
    (((size_t)(b * 4096 + (slot)) * 512) + (size_t)((blk) * 128 + ct * 32 + (e8) * 8))

#define SETUP_TABLE48() \
    if (tid < 48) { \
        float s_, c_; \
        sincosf(TWO_PI * (float)tid / 64.0f, &s_, &c_); \
        wre[tid] = c_; wim[tid] = -s_; \
    }

// ---- forward pass A: FFT over n1 (slots 64*n1+dg), twiddle, x fp32 -> z bf16
extern "C" __global__ void __launch_bounds__(512)
fft_fwd_a(const float* __restrict__ x, short* __restrict__ zre, short* __restrict__ zim) {
    __shared__ __align__(16) _Float16 Lre[64][136];
    __shared__ __align__(16) _Float16 Lim[64][136];
    __shared__ float wre[48], wim[48];
    __shared__ float twr[64], twi[64];
    const int tid = threadIdx.x;
    SETUP_TABLE48();
    DECODE_BCT();   // dg = n2
    if (tid >= 64 && tid < 128) {
        const int s1 = tid - 64;
        float sn, cs;
        sincosf(-(TWO_PI / 4096.0f) * (float)(dg * dr4(s1)), &sn, &cs);
        twr[s1] = cs; twi[s1] = sn;
    }
    for (int idx = tid; idx < 2048; idx += 512) {
        const int n1 = idx >> 5, q = idx & 31, blk = q >> 3, f4 = q & 7;
        const int cl = blk * 32 + f4 * 4;
        const float4 v = *(const float4*)(x + GADDR(n1 * 64 + dg, blk, f4));
        h16x4 hv, hz;
        hv[0] = (_Float16)v.x; hv[1] = (_Float16)v.y;
        hv[2] = (_Float16)v.z; hv[3] = (_Float16)v.w;
        hz[0] = (_Float16)0.f; hz[1] = (_Float16)0.f;
        hz[2] = (_Float16)0.f; hz[3] = (_Float16)0.f;
        *(h16x4*)&Lre[n1][cl] = hv;
        *(h16x4*)&Lim[n1][cl] = hz;
    }
    fft64_dif4v<136>(Lre, Lim, wre, wim, (tid & 31) * 4, tid >> 5);
    for (int idx = tid; idx < 2048; idx += 512) {
        const int s1 = idx >> 5, q = idx & 31, blk = q >> 3, f4 = q & 7;
        const int cl = blk * 32 + f4 * 4;
        const float cs = twr[s1], sn = twi[s1];
        const h16x4 hr = *(const h16x4*)&Lre[s1][cl];
        const h16x4 hi = *(const h16x4*)&Lim[s1][cl];
        bf16x4 pr, pi;
#pragma unroll
        for (int i = 0; i < 4; ++i) {
            const float vr = (float)hr[i], vi = (float)hi[i];
            pr[i] = f2bf(vr * cs - vi * sn);
            pi[i] = f2bf(vr * sn + vi * cs);
        }
        const size_t g = GADDR(s1 * 64 + dg, blk, f4);
        *(bf16x4*)(zre + g) = pr;
        *(bf16x4*)(zim + g) = pi;
    }
}

// ---- forward pass B: FFT over n2 (contiguous slots) + fused fft4_fwd (x1/128)
extern "C" __global__ void __launch_bounds__(512)
fft_fwd_b(short* __restrict__ zre, short* __restrict__ zim) {
    __shared__ __align__(16) _Float16 Lre[64][136];
    __shared__ __align__(16) _Float16 Lim[64][136];
    __shared__ float wre[48], wim[48];
    const int tid = threadIdx.x;
    SETUP_TABLE48();
    DECODE_BCT();   // dg = s1
    for (int idx = tid; idx < 1024; idx += 512) {
        const int n2 = idx >> 4, q = idx & 15, blk = q >> 2, e8 = q & 3;
        const int cl = blk * 32 + e8 * 8;
        const size_t g = GADDR8(dg * 64 + n2, blk, e8);
        const bf16x8 vr = *(const bf16x8*)(zre + g);
        const bf16x8 vi = *(const bf16x8*)(zim + g);
        h16x8 hr, hi;
#pragma unroll
        for (int i = 0; i < 8; ++i) {
            hr[i] = (_Float16)bf2f(vr[i]);
            hi[i] = (_Float16)bf2f(vi[i]);
        }
        *(h16x8*)&Lre[n2][cl] = hr;
        *(h16x8*)&Lim[n2][cl] = hi;
    }
    fft64_dif4v<136>(Lre, Lim, wre, wim, (tid & 31) * 4, tid >> 5);
    // fused fft4 + scale, channel-vectorized: item = (slot, dl-quad), 1/thread
    {
        const int s = tid >> 3, dq = tid & 7;
        const int cb = dq * 4;
        h16x4 R[4], M[4];
#pragma unroll
        for (int qq = 0; qq < 4; ++qq) {
            R[qq] = *(const h16x4*)&Lre[s][cb + qq * 32];
            M[qq] = *(const h16x4*)&Lim[s][cb + qq * 32];
        }
        h16x4 YR[4], YM[4];
        const float sc = 1.0f / 128.0f;
#pragma unroll
        for (int e = 0; e < 4; ++e) {
            const float r0 = (float)R[0][e], r1 = (float)R[1][e];
            const float r2 = (float)R[2][e], r3 = (float)R[3][e];
            const float m0 = (float)M[0][e], m1 = (float)M[1][e];
            const float m2 = (float)M[2][e], m3 = (float)M[3][e];
            YR[0][e] = (_Float16)((r0 + r1 + r2 + r3) * sc);
            YM[0][e] = (_Float16)((m0 + m1 + m2 + m3) * sc);
            YR[1][e] = (_Float16)((r0 + m1 - r2 - m3) * sc);
            YM[1][e] = (_Float16)((m0 - r1 - m2 + r3) * sc);
            YR[2][e] = (_Float16)((r0 - r1 + r2 - r3) * sc);
            YM[2][e] = (_Float16)((m0 - m1 + m2 - m3) * sc);
            YR[3][e] = (_Float16)((r0 - m1 - r2 + m3) * sc);
            YM[3][e] = (_Float16)((m0 + r1 - m2 - r3) * sc);
        }
#pragma unroll
        for (int qq = 0; qq < 4; ++qq) {
            *(h16x4*)&Lre[s][cb + qq * 32] = YR[qq];
            *(h16x4*)&Lim[s][cb + qq * 32] = YM[qq];
        }
    }
    __syncthreads();
    for (int idx = tid; idx < 1024; idx += 512) {
        const int s2 = idx >> 4, q = idx & 15, blk = q >> 2, e8 = q & 3;
        const int cl = blk * 32 + e8 * 8;
        const h16x8 hr = *(const h16x8*)&Lre[s2][cl];
        const h16x8 hi = *(const h16x8*)&Lim[s2][cl];
        bf16x8 pr, pi;
#pragma unroll
        for (int i = 0; i < 8; ++i) {
            pr[i] = f2bf((float)hr[i]);
            pi[i] = f2bf((float)hi[i]);
        }
        const size_t g = GADDR8(dg * 64 + s2, blk, e8);
        *(bf16x8*)(zre + g) = pr;
        *(bf16x8*)(zim + g) = pi;
    }
}

// ---- inverse pass A: fused fft4_inv (x1/128), inverse FFT over k2, twiddle
extern "C" __global__ void __launch_bounds__(512)
fft_inv_a(short* __restrict__ zre, short* __restrict__ zim) {
    __shared__ __align__(16) _Float16 Lre[64][136];
    __shared__ __align__(16) _Float16 Lim[64][136];
    __shared__ float wre[48], wim[48];
    __shared__ float twr[64], twi[64];
    const int tid = threadIdx.x;
    SETUP_TABLE48();
    DECODE_BCT();   // dg = s1
    if (tid >= 64 && tid < 128) {
        const int n2 = tid - 64;
        float sn, cs;
        sincosf((TWO_PI / 4096.0f) * (float)(n2 * dr4(dg)), &sn, &cs);
        twr[n2] = cs; twi[n2] = sn;
    }
    for (int idx = tid; idx < 1024; idx += 512) {
        const int s2 = idx >> 4, q = idx & 15, blk = q >> 2, e8 = q & 3;
        const int cl = blk * 32 + e8 * 8;
        const size_t g = GADDR8(dg * 64 + s2, blk, e8);
        const bf16x8 vr = *(const bf16x8*)(zre + g);
        const bf16x8 vi = *(const bf16x8*)(zim + g);
        h16x8 hr, hi;
#pragma unroll
        for (int i = 0; i < 8; ++i) {
            hr[i] = (_Float16)bf2f(vr[i]);
            hi[i] = (_Float16)bf2f(vi[i]);
        }
        *(h16x8*)&Lre[s2][cl] = hr;
        *(h16x8*)&Lim[s2][cl] = hi;
    }
    __syncthreads();
    // fused inverse fft4 + scale, channel-vectorized: item = (slot, dl-quad)
    {
        const int s = tid >> 3, dq = tid & 7;
        const int cb = dq * 4;
        h16x4 R[4], M[4];
#pragma unroll
        for (int qq = 0; qq < 4; ++qq) {
            R[qq] = *(const h16x4*)&Lre[s][cb + qq * 32];
            M[qq] = *(const h16x4*)&Lim[s][cb + qq * 32];
        }
        h16x4 YR[4], YM[4];
        const float sc = 1.0f / 128.0f;
#pragma unroll
        for (int e = 0; e < 4; ++e) {
            const float r0 = (float)R[0][e], r1 = (float)R[1][e];
            const float r2 = (float)R[2][e], r3 = (float)R[3][e];
            const float m0 = (float)M[0][e], m1 = (float)M[1][e];
            const float m2 = (float)M[2][e], m3 = (float)M[3][e];
            YR[0][e] = (_Float16)((r0 + r1 + r2 + r3) * sc);
            YM[0][e] = (_Float16)((m0 + m1 + m2 + m3) * sc);
            YR[1][e] = (_Float16)((r0 - m1 - r2 + m3) * sc);
            YM[1][e] = (_Float16)((m0 + r1 - m2 - r3) * sc);
            YR[2][e] = (_Float16)((r0 - r1 + r2 - r3) * sc);
            YM[2][e] = (_Float16)((m0 - m1 + m2 - m3) * sc);
            YR[3][e] = (_Float16)((r0 + m1 - r2 - m3) * sc);
            YM[3][e] = (_Float16)((m0 - r1 - m2 + r3) * sc);
        }
#pragma unroll
        for (int qq = 0; qq < 4; ++qq) {
            *(h16x4*)&Lre[s][cb + qq * 32] = YR[qq];
            *(h16x4*)&Lim[s][cb + qq * 32] = YM[qq];
        }
    }
    fft64_dit4v<136>(Lre, Lim, wre, wim, (tid & 31) * 4, tid >> 5);
    for (int idx = tid; idx < 2048; idx += 512) {
        const int n2 = idx >> 5, q = idx & 31, blk = q >> 3, f4 = q & 7;
        const int cl = blk * 32 + f4 * 4;
        const float cs = twr[n2], sn = twi[n2];
        const h16x4 hr = *(const h16x4*)&Lre[n2][cl];
        const h16x4 hi = *(const h16x4*)&Lim[n2][cl];
        bf16x4 pr, pi;
#pragma unroll
        for (int i = 0; i < 4; ++i) {
            const float vr = (float)hr[i], vi = (float)hi[i];
            pr[i] = f2bf(vr * cs - vi * sn);
            pi[i] = f2bf(vr * sn + vi * cs);
        }
        const size_t g = GADDR(dg * 64 + n2, blk, f4);
        *(bf16x4*)(zre + g) = pr;
        *(bf16x4*)(zim + g) = pi;
    }
}

// ---- inverse pass B: inverse FFT over k1, write REAL fp32 into d_out
extern "C" __global__ void __launch_bounds__(512)
fft_inv_b(const short* __restrict__ zre, const short* __restrict__ zim,
          float* __restrict__ out) {
    __shared__ __align__(16) _Float16 Lre[64][136];
    __shared__ __align__(16) _Float16 Lim[64][136];
    __shared__ float wre[48], wim[48];
    const int tid = threadIdx.x;
    SETUP_TABLE48();
    DECODE_BCT();   // dg = n2
    for (int idx = tid; idx < 1024; idx += 512) {
        const int s1 = idx >> 4, q = idx & 15, blk = q >> 2, e8 = q & 3;
        const int cl = blk * 32 + e8 * 8;
        const size_t g = GADDR8(s1 * 64 + dg, blk, e8);
        const bf16x8 vr = *(const bf16x8*)(zre + g);
        const bf16x8 vi = *(const bf16x8*)(zim + g);
        h16x8 hr, hi;
#pragma unroll
        for (int i = 0; i < 8; ++i) {
            hr[i] = (_Float16)bf2f(vr[i]);
            hi[i] = (_Float16)bf2f(vi[i]);
        }
        *(h16x8*)&Lre[s1][cl] = hr;
        *(h16x8*)&Lim[s1][cl] = hi;
    }
    fft64_dit4v<136>(Lre, Lim, wre, wim, (tid & 31) * 4, tid >> 5);
    for (int idx = tid; idx < 2048; idx += 512) {
        const int n1 = idx >> 5, q = idx & 31, blk = q >> 3, f4 = q & 7;
        const int cl = blk * 32 + f4 * 4;
        const h16x4 hr = *(const h16x4*)&Lre[n1][cl];
        float4 o;
        o.x = (float)hr[0]; o.y = (float)hr[1];
        o.z = (float)hr[2]; o.w = (float)hr[3];
        *(float4*)(out + GADDR(n1 * 64 + dg, blk, f4)) = o;
    }
}

// ---------------------------------------------------------------------------
// Weight prep: fold complex 2x2 into W_big bf16 [L][blk][n][k], in d_out.
// ---------------------------------------------------------------------------
extern "C" __global__ void __launch_bounds__(256)
wprep(const float* __restrict__ w1, const float* __restrict__ w2,
      short* __restrict__ wb) {
    const int i4  = blockIdx.x * 256 + threadIdx.x;
    const int k0  = (i4 & 63) * 4;
    const int n   = (i4 >> 6) & 255;
    const int blk = (i4 >> 14) & 3;
    const int L   = i4 >> 16;
    const float* w = L ? w2 : w1;
    bf16x4 pv;
#pragma unroll
    for (int j = 0; j < 4; ++j) {
        const int k = k0 + j;
        float v;
        if (k < 128) {
            v = (n < 128) ? w[blk * 16384 + k * 128 + n]
                          : w[65536 + blk * 16384 + k * 128 + (n - 128)];
        } else {
            v = (n < 128) ? -w[65536 + blk * 16384 + (k - 128) * 128 + n]
                          :  w[blk * 16384 + (k - 128) * 128 + (n - 128)];
        }
        pv[j] = f2bf(v);
    }
    *(bf16x4*)(wb + (size_t)i4 * 4) = pv;
}

// ---------------------------------------------------------------------------
// MFMA block-diagonal complex MLP layer over bf16 planes, in place.
// global_load_lds staging (swizzle on global source addr), double-buffered.
// ---------------------------------------------------------------------------
#define MITER 4

__device__ __forceinline__ void stage_tile(const short* __restrict__ zre,
                                           const short* __restrict__ zim,
                                           char* Abuf, int rowbase, int blk,
                                           int wave, int lane) {
#pragma unroll
    for (int it = 0; it < 4; ++it) {
        const int chunk = wave * 256 + it * 64 + lane;   // 16B chunk id, 0..2047
        const int row   = chunk >> 5;
        const unsigned kbyte = ((unsigned)((chunk & 31) << 4)) ^ ((unsigned)((row & 7) << 4));
        const int k0 = (int)(kbyte >> 1);                // element k, multiple of 8
        const short* src = (k0 < 128) ? zre : zim;
        const size_t g = (size_t)(rowbase + row) * 512 + blk * 128 + (k0 & 127);
        unsigned* lp = (unsigned*)(Abuf + (wave * 4096 + it * 1024));  // wave-uniform
        __builtin_amdgcn_global_load_lds((const unsigned*)(src + g), lp, 16, 0, 0);
    }
}

template<int LAYER>
__global__ void __launch_bounds__(512)
mlp_mfma(short* __restrict__ zre, short* __restrict__ zim,
         const short* __restrict__ wb, const float* __restrict__ bias) {
    __shared__ __align__(16) char As[2][64 * 256 * 2];   // 2 x 32 KB bf16, swizzled

    const int blk  = blockIdx.y;
    const int tid  = threadIdx.x;
    const int wave = tid >> 6;
    const int lane = tid & 63;
    const int lrow = lane & 15;
    const int lk   = lane >> 4;

    bf16x8 Bf[2][8];
#pragma unroll
    for (int nt = 0; nt < 2; ++nt) {
        const int n = wave * 32 + nt * 16 + lrow;
#pragma unroll
        for (int ks = 0; ks < 8; ++ks) {
            Bf[nt][ks] = *(const bf16x8*)(wb + ((size_t)(blk * 256 + n) * 256 + ks * 32 + lk * 8));
        }
    }

    float bv[2];
#pragma unroll
    for (int nt = 0; nt < 2; ++nt) {
        const int n = wave * 32 + nt * 16 + lrow;
        bv[nt] = (n < 128) ? bias[blk * 128 + n] : bias[512 + blk * 128 + (n - 128)];
    }

    stage_tile(zre, zim, As[0], blockIdx.x * MITER * 64, blk, wave, lane);

    for (int t = 0; t < MITER; ++t) {
        __syncthreads();

        if (t + 1 < MITER)
            stage_tile(zre, zim, As[(t + 1) & 1],
                       (blockIdx.x * MITER + t + 1) * 64, blk, wave, lane);

        const char* Ab = As[t & 1];
        const int rowbase = (blockIdx.x * MITER + t) * 64;

        f32x4 acc[4][2];
#pragma unroll
        for (int mt = 0; mt < 4; ++mt)
#pragma unroll
            for (int nt = 0; nt < 2; ++nt)
                acc[mt][nt] = (f32x4){0.f, 0.f, 0.f, 0.f};

#pragma unroll
        for (int ks = 0; ks < 8; ++ks) {
            bf16x8 af[4];
#pragma unroll
            for (int mt = 0; mt < 4; ++mt) {
                const int row = mt * 16 + lrow;
                const int k0  = ks * 32 + lk * 8;
                const unsigned byteoff =
                    ((unsigned)(row * 512 + k0 * 2)) ^ ((unsigned)((row & 7) << 4));
                af[mt] = *(const bf16x8*)(Ab + byteoff);
            }
#pragma unroll
            for (int mt = 0; mt < 4; ++mt)
#pragma unroll
                for (int nt = 0; nt < 2; ++nt)
                    acc[mt][nt] = __builtin_amdgcn_mfma_f32_16x16x32_bf16(
                        af[mt], Bf[nt][ks], acc[mt][nt], 0, 0, 0);
        }

#pragma unroll
        for (int nt = 0; nt < 2; ++nt) {
            const int n = wave * 32 + nt * 16 + lrow;
            short* dst = (n < 128) ? zre : zim;
            const int col = blk * 128 + (n & 127);
#pragma unroll
            for (int mt = 0; mt < 4; ++mt) {
#pragma unroll
                for (int r = 0; r < 4; ++r) {
                    const int row = rowbase + mt * 16 + lk * 4 + r;
                    float v = acc[mt][nt][r] + bv[nt];
                    if (LAYER == 1) {
                        v = fmaxf(v, 0.0f);
                    } else {
                        v = (v > 0.01f) ? v - 0.01f : ((v < -0.01f) ? v + 0.01f : 0.0f);
                    }
                    dst[(size_t)row * 512 + col] = f2bf(v);
                }
            }
        }
    }
}

extern "C" void kernel_launch(void* const* d_in, const int* in_sizes, int n_in,
                              void* d_out, int out_size, void* d_ws, size_t ws_size,
                              hipStream_t stream) {
    const float* x  = (const float*)d_in[0];
    const float* w1 = (const float*)d_in[1];
    const float* w2 = (const float*)d_in[2];
    const float* b1 = (const float*)d_in[3];
    const float* b2 = (const float*)d_in[4];

    float* out = (float*)d_out;
    short* zre = (short*)d_ws;            // bf16 real plane, 32 MiB
    short* zim = zre + 16777216;          // bf16 imag plane, 32 MiB
    short* wb  = (short*)d_out;           // 1 MiB W_big scratch inside d_out
    const size_t WB_L = 4ull * 256 * 256;

    wprep<<<512, 256, 0, stream>>>(w1, w2, wb);

    // forward FFT2 (ortho), radix-4 four-step; fft4+scale fused into pass B
    fft_fwd_a<<<2048, 512, 0, stream>>>(x, zre, zim);
    fft_fwd_b<<<2048, 512, 0, stream>>>(zre, zim);

    // block-diagonal complex MLP via MFMA, one dispatch per layer, in place
    mlp_mfma<1><<<dim3(32768 / (64 * MITER), 4), 512, 0, stream>>>(zre, zim, wb, b1);
    mlp_mfma<2><<<dim3(32768 / (64 * MITER), 4), 512, 0, stream>>>(zre, zim, wb + WB_L, b2);

    // inverse FFT2 (ortho), radix-4; fft4_inv+scale fused into pass A
    fft_inv_a<<<2048, 512, 0, stream>>>(zre, zim);
    fft_inv_b<<<2048, 512, 0, stream>>>(zre, zim, out);
}